// Round 3
// baseline (44.405 us; speedup 1.0000x reference)
//
#include <hip/hip_runtime.h>

#define HW 2304          // 48*48
#define HW4 576          // HW/4
#define PART_STRIDE 2308 // 2304 A-partials + 1 sq, padded to mult of 4
#define R2 8             // second-level row groups

// Stage 1: per-block partial sums, 4-batch manual unroll so 8 independent
// 16B loads are in flight per thread (breaks the vmcnt(0)-per-iter serial
// chain the 12-VGPR rolled loop had). Each thread owns 4 fixed hw positions.
__global__ __launch_bounds__(576) void sc_stage1(
    const float4* __restrict__ out4, const float4* __restrict__ tgt4,
    float* __restrict__ part, int B, int NB)
{
    int tid = threadIdx.x;
    int blk = blockIdx.x;
    size_t stride = (size_t)NB * HW4;
    size_t base = (size_t)blk * HW4 + tid;
    float a0 = 0.f, a1 = 0.f, a2 = 0.f, a3 = 0.f, sq = 0.f;

    int b = blk;
    for (; b + 3 * NB < B; b += 4 * NB, base += 4 * stride) {
        float4 o0 = out4[base];
        float4 o1 = out4[base + stride];
        float4 o2 = out4[base + 2 * stride];
        float4 o3 = out4[base + 3 * stride];
        float4 t0 = tgt4[base];
        float4 t1 = tgt4[base + stride];
        float4 t2 = tgt4[base + 2 * stride];
        float4 t3 = tgt4[base + 3 * stride];
        float d;
        d = o0.x - t0.x; sq = fmaf(d, d, sq); a0 += fabsf(d);
        d = o0.y - t0.y; sq = fmaf(d, d, sq); a1 += fabsf(d);
        d = o0.z - t0.z; sq = fmaf(d, d, sq); a2 += fabsf(d);
        d = o0.w - t0.w; sq = fmaf(d, d, sq); a3 += fabsf(d);
        d = o1.x - t1.x; sq = fmaf(d, d, sq); a0 += fabsf(d);
        d = o1.y - t1.y; sq = fmaf(d, d, sq); a1 += fabsf(d);
        d = o1.z - t1.z; sq = fmaf(d, d, sq); a2 += fabsf(d);
        d = o1.w - t1.w; sq = fmaf(d, d, sq); a3 += fabsf(d);
        d = o2.x - t2.x; sq = fmaf(d, d, sq); a0 += fabsf(d);
        d = o2.y - t2.y; sq = fmaf(d, d, sq); a1 += fabsf(d);
        d = o2.z - t2.z; sq = fmaf(d, d, sq); a2 += fabsf(d);
        d = o2.w - t2.w; sq = fmaf(d, d, sq); a3 += fabsf(d);
        d = o3.x - t3.x; sq = fmaf(d, d, sq); a0 += fabsf(d);
        d = o3.y - t3.y; sq = fmaf(d, d, sq); a1 += fabsf(d);
        d = o3.z - t3.z; sq = fmaf(d, d, sq); a2 += fabsf(d);
        d = o3.w - t3.w; sq = fmaf(d, d, sq); a3 += fabsf(d);
    }
    for (; b < B; b += NB, base += stride) {   // tail (empty for B=8192,NB=1024)
        float4 o = out4[base];
        float4 t = tgt4[base];
        float d;
        d = o.x - t.x; sq = fmaf(d, d, sq); a0 += fabsf(d);
        d = o.y - t.y; sq = fmaf(d, d, sq); a1 += fabsf(d);
        d = o.z - t.z; sq = fmaf(d, d, sq); a2 += fabsf(d);
        d = o.w - t.w; sq = fmaf(d, d, sq); a3 += fabsf(d);
    }

    float* pbase = part + (size_t)blk * PART_STRIDE;
    ((float4*)pbase)[tid] = make_float4(a0, a1, a2, a3);

    #pragma unroll
    for (int off = 32; off; off >>= 1) sq += __shfl_down(sq, off);
    __shared__ float wsum[9];
    int wid = tid >> 6;
    if ((tid & 63) == 0) wsum[wid] = sq;
    __syncthreads();
    if (tid == 0) {
        float s = 0.f;
        #pragma unroll
        for (int w = 0; w < 9; ++w) s += wsum[w];
        pbase[HW] = s;
    }
}

// Stage 2 (v3): 36 column-blocks x R2 row-groups + 1 = 289 blocks x 256.
// Block (c,r) reduces its NB/R2 rows for 64 columns -> part2[r][hw]
// (un-normalized). Block 288 reduces the sq partials -> MSE into out[0]
// (plain store: idempotent across graph replays).
__global__ __launch_bounds__(256) void sc_stage2(
    const float* __restrict__ part, float* __restrict__ part2,
    float* __restrict__ out, int NB, float invN)
{
    __shared__ float red[4][64];
    int blk  = blockIdx.x;
    int lane = threadIdx.x & 63;
    int grp  = threadIdx.x >> 6;   // 0..3
    if (blk < 36 * R2) {
        int c = blk / R2, r = blk % R2;
        int hw = c * 64 + lane;          // coalesced per wave
        int rows = NB / R2;
        int r0 = r * rows;
        float s = 0.f;
        for (int k = grp; k < rows; k += 4)
            s += part[(size_t)(r0 + k) * PART_STRIDE + hw];
        red[grp][lane] = s;
        __syncthreads();
        if (grp == 0)
            part2[r * HW + hw] = red[0][lane] + red[1][lane] +
                                 red[2][lane] + red[3][lane];
    } else {
        float s = 0.f;
        for (int k = threadIdx.x; k < NB; k += 256)
            s += part[(size_t)k * PART_STRIDE + HW];
        #pragma unroll
        for (int off = 32; off; off >>= 1) s += __shfl_down(s, off);
        if (lane == 0) red[0][grp] = s;
        __syncthreads();
        if (threadIdx.x == 0)
            out[0] = (red[0][0] + red[0][1] + red[0][2] + red[0][3]) * invN;
    }
}

// Stage 3: one block per (i,j). A[hw] folded in on the fly from part2
// (8 x 2304 floats, L2-hot). out += 0.5*mu*l1^2 (54 atomic adds;
// fp ordering noise ~1e-7 << threshold).
__global__ __launch_bounds__(256) void sc_stage3(
    const float* __restrict__ part2, const float* __restrict__ psu,
    const float* __restrict__ mu, float* __restrict__ out, float invB)
{
    int j = blockIdx.x;
    int tid = threadIdx.x;
    const float* p = psu + (size_t)j * HW;
    float s = 0.f;
    for (int hw = tid; hw < HW; hw += 256) {
        float a = 0.f;
        #pragma unroll
        for (int r = 0; r < R2; ++r) a += part2[r * HW + hw];
        s += a * fabsf(p[hw]);
    }
    #pragma unroll
    for (int off = 32; off; off >>= 1) s += __shfl_down(s, off);
    __shared__ float wsum[4];
    if ((tid & 63) == 0) wsum[tid >> 6] = s;
    __syncthreads();
    if (tid == 0) {
        float l1 = (wsum[0] + wsum[1] + wsum[2] + wsum[3]) * invB * (1.0f / HW);
        float contrib = 0.5f * mu[j] * l1 * l1;   // GAMMA = 1
        atomicAdd(out, contrib);
    }
}

extern "C" void kernel_launch(void* const* d_in, const int* in_sizes, int n_in,
                              void* d_out, int out_size, void* d_ws, size_t ws_size,
                              hipStream_t stream)
{
    const float* outp = (const float*)d_in[0];
    const float* tgtp = (const float*)d_in[1];
    const float* psu  = (const float*)d_in[2];
    const float* mu   = (const float*)d_in[3];

    int B   = in_sizes[0] / HW;     // 8192
    int nij = in_sizes[3];          // 54

    int NB = 1024;                  // stage-1 blocks; shrink if ws too small
    while (NB > 64 &&
           ((size_t)NB * PART_STRIDE + (size_t)R2 * HW) * sizeof(float) > ws_size)
        NB >>= 1;

    float* part  = (float*)d_ws;
    float* part2 = part + (size_t)NB * PART_STRIDE;
    float invN   = 1.0f / ((float)B * (float)HW);
    float invB   = 1.0f / (float)B;

    sc_stage1<<<NB, 576, 0, stream>>>((const float4*)outp, (const float4*)tgtp,
                                      part, B, NB);
    sc_stage2<<<36 * R2 + 1, 256, 0, stream>>>(part, part2, (float*)d_out,
                                               NB, invN);
    sc_stage3<<<nij, 256, 0, stream>>>(part2, psu, mu, (float*)d_out, invB);
}

// Round 4
// 44.367 us; speedup vs baseline: 1.0009x; 1.0009x over previous
//
#include <hip/hip_runtime.h>

#define HW 2304          // 48*48
#define HW4 576          // HW/4
#define PART_STRIDE 2308 // 2304 A-partials + 1 sq, padded to mult of 4
#define R2 8             // second-level row groups

// Stage 1: per-block partial sums. Each thread owns 4 fixed hw positions.
// 4-batch chunks: all 8 float4 loads are issued BEFORE the compiler fence,
// so they stay clustered (one waitcnt per chunk, 128B/lane in flight)
// instead of being register-minimized into a serial load->use chain
// (round-3 failure: VGPR=32 proved the compiler re-interleaved them).
__global__ __launch_bounds__(576, 4) void sc_stage1(
    const float4* __restrict__ out4, const float4* __restrict__ tgt4,
    float* __restrict__ part, int B, int NB)
{
    int tid = threadIdx.x;
    int blk = blockIdx.x;
    size_t stride = (size_t)NB * HW4;
    size_t base = (size_t)blk * HW4 + tid;
    float a0 = 0.f, a1 = 0.f, a2 = 0.f, a3 = 0.f, sq = 0.f;

    int b = blk;
    for (; b + 3 * NB < B; b += 4 * NB, base += 4 * stride) {
        float4 o0 = out4[base];
        float4 o1 = out4[base + stride];
        float4 o2 = out4[base + 2 * stride];
        float4 o3 = out4[base + 3 * stride];
        float4 t0 = tgt4[base];
        float4 t1 = tgt4[base + stride];
        float4 t2 = tgt4[base + 2 * stride];
        float4 t3 = tgt4[base + 3 * stride];
        asm volatile("" ::: "memory");   // loads may not sink below this
        float d;
        d = o0.x - t0.x; sq = fmaf(d, d, sq); a0 += fabsf(d);
        d = o0.y - t0.y; sq = fmaf(d, d, sq); a1 += fabsf(d);
        d = o0.z - t0.z; sq = fmaf(d, d, sq); a2 += fabsf(d);
        d = o0.w - t0.w; sq = fmaf(d, d, sq); a3 += fabsf(d);
        d = o1.x - t1.x; sq = fmaf(d, d, sq); a0 += fabsf(d);
        d = o1.y - t1.y; sq = fmaf(d, d, sq); a1 += fabsf(d);
        d = o1.z - t1.z; sq = fmaf(d, d, sq); a2 += fabsf(d);
        d = o1.w - t1.w; sq = fmaf(d, d, sq); a3 += fabsf(d);
        d = o2.x - t2.x; sq = fmaf(d, d, sq); a0 += fabsf(d);
        d = o2.y - t2.y; sq = fmaf(d, d, sq); a1 += fabsf(d);
        d = o2.z - t2.z; sq = fmaf(d, d, sq); a2 += fabsf(d);
        d = o2.w - t2.w; sq = fmaf(d, d, sq); a3 += fabsf(d);
        d = o3.x - t3.x; sq = fmaf(d, d, sq); a0 += fabsf(d);
        d = o3.y - t3.y; sq = fmaf(d, d, sq); a1 += fabsf(d);
        d = o3.z - t3.z; sq = fmaf(d, d, sq); a2 += fabsf(d);
        d = o3.w - t3.w; sq = fmaf(d, d, sq); a3 += fabsf(d);
    }
    for (; b < B; b += NB, base += stride) {   // tail (empty for B=8192,NB=1024)
        float4 o = out4[base];
        float4 t = tgt4[base];
        float d;
        d = o.x - t.x; sq = fmaf(d, d, sq); a0 += fabsf(d);
        d = o.y - t.y; sq = fmaf(d, d, sq); a1 += fabsf(d);
        d = o.z - t.z; sq = fmaf(d, d, sq); a2 += fabsf(d);
        d = o.w - t.w; sq = fmaf(d, d, sq); a3 += fabsf(d);
    }

    float* pbase = part + (size_t)blk * PART_STRIDE;
    ((float4*)pbase)[tid] = make_float4(a0, a1, a2, a3);

    #pragma unroll
    for (int off = 32; off; off >>= 1) sq += __shfl_down(sq, off);
    __shared__ float wsum[9];
    int wid = tid >> 6;
    if ((tid & 63) == 0) wsum[wid] = sq;
    __syncthreads();
    if (tid == 0) {
        float s = 0.f;
        #pragma unroll
        for (int w = 0; w < 9; ++w) s += wsum[w];
        pbase[HW] = s;
    }
}

// Stage 2: 36 column-blocks x R2 row-groups + 1 = 289 blocks x 256.
// Block (c,r) reduces its NB/R2 rows for 64 columns -> part2[r][hw]
// (un-normalized). Block 288 reduces the sq partials -> MSE into out[0]
// (plain store: idempotent across graph replays).
__global__ __launch_bounds__(256) void sc_stage2(
    const float* __restrict__ part, float* __restrict__ part2,
    float* __restrict__ out, int NB, float invN)
{
    __shared__ float red[4][64];
    int blk  = blockIdx.x;
    int lane = threadIdx.x & 63;
    int grp  = threadIdx.x >> 6;   // 0..3
    if (blk < 36 * R2) {
        int c = blk / R2, r = blk % R2;
        int hw = c * 64 + lane;          // coalesced per wave
        int rows = NB / R2;
        int r0 = r * rows;
        float s = 0.f;
        for (int k = grp; k < rows; k += 4)
            s += part[(size_t)(r0 + k) * PART_STRIDE + hw];
        red[grp][lane] = s;
        __syncthreads();
        if (grp == 0)
            part2[r * HW + hw] = red[0][lane] + red[1][lane] +
                                 red[2][lane] + red[3][lane];
    } else {
        float s = 0.f;
        for (int k = threadIdx.x; k < NB; k += 256)
            s += part[(size_t)k * PART_STRIDE + HW];
        #pragma unroll
        for (int off = 32; off; off >>= 1) s += __shfl_down(s, off);
        if (lane == 0) red[0][grp] = s;
        __syncthreads();
        if (threadIdx.x == 0)
            out[0] = (red[0][0] + red[0][1] + red[0][2] + red[0][3]) * invN;
    }
}

// Stage 3: one block per (i,j). A[hw] folded in on the fly from part2
// (8 x 2304 floats, L2-hot). out += 0.5*mu*l1^2 (54 atomic adds;
// fp ordering noise ~1e-7 << threshold).
__global__ __launch_bounds__(256) void sc_stage3(
    const float* __restrict__ part2, const float* __restrict__ psu,
    const float* __restrict__ mu, float* __restrict__ out, float invB)
{
    int j = blockIdx.x;
    int tid = threadIdx.x;
    const float* p = psu + (size_t)j * HW;
    float s = 0.f;
    for (int hw = tid; hw < HW; hw += 256) {
        float a = 0.f;
        #pragma unroll
        for (int r = 0; r < R2; ++r) a += part2[r * HW + hw];
        s += a * fabsf(p[hw]);
    }
    #pragma unroll
    for (int off = 32; off; off >>= 1) s += __shfl_down(s, off);
    __shared__ float wsum[4];
    if ((tid & 63) == 0) wsum[tid >> 6] = s;
    __syncthreads();
    if (tid == 0) {
        float l1 = (wsum[0] + wsum[1] + wsum[2] + wsum[3]) * invB * (1.0f / HW);
        float contrib = 0.5f * mu[j] * l1 * l1;   // GAMMA = 1
        atomicAdd(out, contrib);
    }
}

extern "C" void kernel_launch(void* const* d_in, const int* in_sizes, int n_in,
                              void* d_out, int out_size, void* d_ws, size_t ws_size,
                              hipStream_t stream)
{
    const float* outp = (const float*)d_in[0];
    const float* tgtp = (const float*)d_in[1];
    const float* psu  = (const float*)d_in[2];
    const float* mu   = (const float*)d_in[3];

    int B   = in_sizes[0] / HW;     // 8192
    int nij = in_sizes[3];          // 54

    int NB = 1024;                  // stage-1 blocks; shrink if ws too small
    while (NB > 64 &&
           ((size_t)NB * PART_STRIDE + (size_t)R2 * HW) * sizeof(float) > ws_size)
        NB >>= 1;

    float* part  = (float*)d_ws;
    float* part2 = part + (size_t)NB * PART_STRIDE;
    float invN   = 1.0f / ((float)B * (float)HW);
    float invB   = 1.0f / (float)B;

    sc_stage1<<<NB, 576, 0, stream>>>((const float4*)outp, (const float4*)tgtp,
                                      part, B, NB);
    sc_stage2<<<36 * R2 + 1, 256, 0, stream>>>(part, part2, (float*)d_out,
                                               NB, invN);
    sc_stage3<<<nij, 256, 0, stream>>>(part2, psu, mu, (float*)d_out, invB);
}